// Round 10
// baseline (356.189 us; speedup 1.0000x reference)
//
#include <hip/hip_runtime.h>

#define NODES 4096
#define NN 16777216ULL

typedef float f32x4 __attribute__((ext_vector_type(4)));
typedef __bf16 bf16x4 __attribute__((ext_vector_type(4)));
typedef __bf16 bf16x8 __attribute__((ext_vector_type(8)));
typedef unsigned short u16x8 __attribute__((ext_vector_type(8)));
typedef unsigned short u16x4 __attribute__((ext_vector_type(4)));

__device__ __forceinline__ unsigned short f2bf(float x) {
    unsigned u = __builtin_bit_cast(unsigned, x);
    return (unsigned short)((u + 0x7fffu + ((u >> 16) & 1u)) >> 16);
}

// ---- stage A: h = tanh(x@Wm + bm), stored k-blocked bf16: hB[n/8][64 d][8 n]
__global__ __launch_bounds__(256) void prep_h(
    const float* __restrict__ f0, const float* __restrict__ f1,
    const float* __restrict__ Wm0, const float* __restrict__ bm0,
    const float* __restrict__ Wm1, const float* __restrict__ bm1,
    unsigned short* __restrict__ hB0, unsigned short* __restrict__ hB1)
{
    const int d = threadIdx.x & 63;
    int n = blockIdx.x * 4 + (threadIdx.x >> 6);
    n = __builtin_amdgcn_readfirstlane(n);
    const float* r0 = f0 + (size_t)n * 256;
    float a0 = bm0[d];
#pragma unroll 8
    for (int k = 0; k < 256; ++k) a0 = fmaf(r0[k], Wm0[k * 64 + d], a0);
    hB0[((size_t)(n >> 3)) * 512 + d * 8 + (n & 7)] = f2bf(tanhf(a0));
    const float* r1 = f1 + (size_t)n * 128;
    float a1 = bm1[d];
#pragma unroll 8
    for (int k = 0; k < 128; ++k) a1 = fmaf(r1[k], Wm1[k * 64 + d], a1);
    hB1[((size_t)(n >> 3)) * 512 + d * 8 + (n & 7)] = f2bf(tanhf(a1));
}

// ---- adjacency f32 -> bf16 conversion (copy-shaped streaming; also a BW probe)
// Per instruction: 64 lanes x 16B contiguous = 1KB read; 16 independent iters.
__global__ __launch_bounds__(256) void cvt_adj(
    const float* __restrict__ adjS, const float* __restrict__ adjM,
    const float* __restrict__ adjK, unsigned short* __restrict__ dst)
{
    const int m = blockIdx.y;
    const float* src = m < 3 ? adjM + (size_t)m * NN
                     : m < 5 ? adjK + (size_t)(m - 3) * NN
                             : adjS + (size_t)(m - 5) * NN;
    unsigned short* d = dst + (size_t)m * NN;
    const size_t base = (size_t)blockIdx.x * 16384 + (size_t)threadIdx.x * 4;
#pragma unroll
    for (int i = 0; i < 16; ++i) {
        const size_t idx = base + (size_t)i * 1024;
        f32x4 v = *(const f32x4*)(src + idx);
        u16x4 o = { f2bf(v[0]), f2bf(v[1]), f2bf(v[2]), f2bf(v[3]) };
        *(u16x4*)(d + idx) = o;
    }
}

// ---- adjacency GEMM (bf16 A): r8 structure, chunk = 128 k ------------------
// Block = 64 rows x 64 cols, 4 waves; wave w computes rows w*16..+15. Per
// chunk: A [64r][128k] bf16 16KB + B (k-blocked hB) 16KB, double-buffered
// (64KB LDS -> 2 blocks/CU). 8 x 16B loads/thread/chunk pinned BEFORE the
// barrier (in flight across compute). Raw sums atomicAdd'ed (k-split adders);
// tanh deferred. Swizzles (both-sides, reg-staged): A byte ^= (r&7)<<4 within
// 256B row; B byte ^= kb<<4 within 1KB k-block.
__global__ __launch_bounds__(256) void adj_gemm_b16(
    const unsigned short* __restrict__ adjB, int slotBase,
    const unsigned short* __restrict__ hBa, const unsigned short* __restrict__ hBb,
    int split, float* __restrict__ outBase, int khBits)
{
    __shared__ __align__(16) char smem[2][32768];   // [buf][A 16KB | B 16KB]

    const int job = blockIdx.y;
    const unsigned short* adj = adjB + (size_t)(slotBase + job) * NN;
    const unsigned short* hB = (job < split) ? hBa : hBb;

    const int group = blockIdx.x >> khBits;
    const int kh = blockIdx.x & ((1 << khBits) - 1);
    const int n0 = group * 64;
    const int klen = NODES >> khBits;
    const int kbeg = kh * klen;
    const int nc = klen >> 7;            // chunks of 128 k

    const int t = threadIdx.x;
    const int lane = t & 63, w = t >> 6;
    const int fr = lane & 15, fg = lane >> 4;

    // A staging: granule g -> row (t>>4)+g*16, 16B at colbyte (t&15)*16
    const char* aSrcT = (const char*)adj
        + ((size_t)(n0 + (t >> 4)) * NODES + kbeg) * 2 + (size_t)(t & 15) * 16;
    // B staging: k-blocked contiguous
    const char* bSrcT = (const char*)hB + ((size_t)(kbeg >> 3)) * 1024 + (size_t)t * 16;

    int aw[4];
#pragma unroll
    for (int g = 0; g < 4; ++g) {
        const int r = (t >> 4) + g * 16;
        aw[g] = r * 256 + (((t & 15) * 16) ^ ((r & 7) << 4));
    }
    int bw[4];
#pragma unroll
    for (int j = 0; j < 4; ++j) {
        const int L = (t + 256 * j) * 16;
        const int kb = L >> 10;
        const int d = (L >> 4) & 63;
        bw[j] = 16384 + kb * 1024 + ((d * 16) ^ (kb << 4));
    }

    u16x8 RAa0, RAa1, RAa2, RAa3, RAb0, RAb1, RAb2, RAb3;
    u16x8 RBa0, RBa1, RBa2, RBa3, RBb0, RBb1, RBb2, RBb3;

#define LOADXB(P, c) {                                                       \
    P##a0 = *(const u16x8*)(aSrcT + 0 * 131072 + (size_t)(c) * 256);         \
    P##a1 = *(const u16x8*)(aSrcT + 1 * 131072 + (size_t)(c) * 256);         \
    P##a2 = *(const u16x8*)(aSrcT + 2 * 131072 + (size_t)(c) * 256);         \
    P##a3 = *(const u16x8*)(aSrcT + 3 * 131072 + (size_t)(c) * 256);         \
    P##b0 = *(const u16x8*)(bSrcT + 0 * 4096 + (size_t)(c) * 16384);         \
    P##b1 = *(const u16x8*)(bSrcT + 1 * 4096 + (size_t)(c) * 16384);         \
    P##b2 = *(const u16x8*)(bSrcT + 2 * 4096 + (size_t)(c) * 16384);         \
    P##b3 = *(const u16x8*)(bSrcT + 3 * 4096 + (size_t)(c) * 16384); }

#define STOREXB(P, buf) {                                                    \
    *(u16x8*)((buf) + aw[0]) = P##a0;  *(u16x8*)((buf) + aw[1]) = P##a1;     \
    *(u16x8*)((buf) + aw[2]) = P##a2;  *(u16x8*)((buf) + aw[3]) = P##a3;     \
    *(u16x8*)((buf) + bw[0]) = P##b0;  *(u16x8*)((buf) + bw[1]) = P##b1;     \
    *(u16x8*)((buf) + bw[2]) = P##b2;  *(u16x8*)((buf) + bw[3]) = P##b3; }

    f32x4 acc0 = {0.f,0.f,0.f,0.f}, acc1 = {0.f,0.f,0.f,0.f};
    f32x4 acc2 = {0.f,0.f,0.f,0.f}, acc3 = {0.f,0.f,0.f,0.f};

    const int arow = w * 16 + fr;
    const int aswz = (fr & 7) << 4;

#define COMPUTEB(buf) {                                                      \
    _Pragma("unroll")                                                        \
    for (int ks = 0; ks < 4; ++ks) {                                         \
        u16x8 a16 = *(const u16x8*)((buf) + arow * 256 + ((ks * 64 + fg * 16) ^ aswz)); \
        bf16x8 af = __builtin_bit_cast(bf16x8, a16);                         \
        const int kb = ks * 4 + fg;                                          \
        u16x8 b0 = *(const u16x8*)((buf) + 16384 + kb * 1024 + (((0 * 16 + fr) * 16) ^ (kb << 4))); \
        acc0 = __builtin_amdgcn_mfma_f32_16x16x32_bf16(af, __builtin_bit_cast(bf16x8, b0), acc0, 0, 0, 0); \
        u16x8 b1 = *(const u16x8*)((buf) + 16384 + kb * 1024 + (((1 * 16 + fr) * 16) ^ (kb << 4))); \
        acc1 = __builtin_amdgcn_mfma_f32_16x16x32_bf16(af, __builtin_bit_cast(bf16x8, b1), acc1, 0, 0, 0); \
        u16x8 b2 = *(const u16x8*)((buf) + 16384 + kb * 1024 + (((2 * 16 + fr) * 16) ^ (kb << 4))); \
        acc2 = __builtin_amdgcn_mfma_f32_16x16x32_bf16(af, __builtin_bit_cast(bf16x8, b2), acc2, 0, 0, 0); \
        u16x8 b3 = *(const u16x8*)((buf) + 16384 + kb * 1024 + (((3 * 16 + fr) * 16) ^ (kb << 4))); \
        acc3 = __builtin_amdgcn_mfma_f32_16x16x32_bf16(af, __builtin_bit_cast(bf16x8, b3), acc3, 0, 0, 0); \
    } }

    // prologue: chunk 0 -> buf0
    LOADXB(RA, 0);
    STOREXB(RA, smem[0]);

    for (int c = 0; c < nc; c += 2) {
        LOADXB(RB, c + 1);               // pinned before barrier
        __syncthreads();
        COMPUTEB(smem[0]);
        STOREXB(RB, smem[1]);
        if (c + 2 < nc) LOADXB(RA, c + 2);
        __syncthreads();
        COMPUTEB(smem[1]);
        if (c + 2 < nc) STOREXB(RA, smem[0]);
    }

#undef LOADXB
#undef STOREXB
#undef COMPUTEB

    float* C = outBase + (size_t)job * (NODES * 64);
    float* Cw = C + (size_t)(n0 + w * 16 + fg * 4) * 64 + fr;
#pragma unroll
    for (int j = 0; j < 4; ++j) {
        atomicAdd(&Cw[j * 64 + 0],  acc0[j]);
        atomicAdd(&Cw[j * 64 + 16], acc1[j]);
        atomicAdd(&Cw[j * 64 + 32], acc2[j]);
        atomicAdd(&Cw[j * 64 + 48], acc3[j]);
    }
}

// ---- adjacency GEMM (f32 A): round-8 kernel verbatim (fallback path) -------
__global__ __launch_bounds__(256) void adj_gemm_f32(
    const float* __restrict__ A0, const float* __restrict__ A1,
    const float* __restrict__ A2, const float* __restrict__ A3,
    const float* __restrict__ A4,
    const unsigned short* __restrict__ hBa, const unsigned short* __restrict__ hBb,
    int split, float* __restrict__ outBase)
{
    __shared__ __align__(16) char smem[2][16384];

    const int job = blockIdx.y;
    const float* adj = job == 0 ? A0 : job == 1 ? A1 : job == 2 ? A2 : job == 3 ? A3 : A4;
    const unsigned short* hB = (job < split) ? hBa : hBb;

    const int group = blockIdx.x >> 1;
    const int kh = blockIdx.x & 1;
    const int n0 = group * 64;
    const int kbeg = kh * 2048;

    const int t = threadIdx.x;
    const int lane = t & 63, w = t >> 6;
    const int fr = lane & 15, fg = lane >> 4;

    const char* aSrcT = (const char*)adj
        + ((size_t)(n0 + (t >> 4)) * NODES + kbeg) * 4 + (size_t)(t & 15) * 16;
    const char* bSrcT = (const char*)hB + ((size_t)(kbeg >> 3)) * 1024 + (size_t)t * 16;

    int aw[4];
#pragma unroll
    for (int g = 0; g < 4; ++g) {
        const int r = g * 16 + (t >> 4);
        aw[g] = r * 128 + ((((t & 15) * 8)) ^ ((r & 7) << 4));
    }
    int bw[2];
#pragma unroll
    for (int j = 0; j < 2; ++j) {
        const int L = (t + 256 * j) * 16;
        const int kb = L >> 10;
        const int d = (L >> 4) & 63;
        bw[j] = 8192 + kb * 1024 + ((d * 16) ^ (kb << 4));
    }

    f32x4 RAa0, RAa1, RAa2, RAa3, RAb0, RAb1;
    f32x4 RBa0, RBa1, RBa2, RBa3, RBb0, RBb1;

#define LOADX(P, c) {                                                        \
    P##a0 = *(const f32x4*)(aSrcT + 0 * 262144 + (c) * 256);                 \
    P##a1 = *(const f32x4*)(aSrcT + 1 * 262144 + (c) * 256);                 \
    P##a2 = *(const f32x4*)(aSrcT + 2 * 262144 + (c) * 256);                 \
    P##a3 = *(const f32x4*)(aSrcT + 3 * 262144 + (c) * 256);                 \
    P##b0 = *(const f32x4*)(bSrcT + (c) * 8192);                             \
    P##b1 = *(const f32x4*)(bSrcT + 4096 + (c) * 8192); }

#define STOREX(P, buf) {                                                     \
    *(u16x4*)((buf) + aw[0]) = __builtin_bit_cast(u16x4, __builtin_convertvector(P##a0, bf16x4)); \
    *(u16x4*)((buf) + aw[1]) = __builtin_bit_cast(u16x4, __builtin_convertvector(P##a1, bf16x4)); \
    *(u16x4*)((buf) + aw[2]) = __builtin_bit_cast(u16x4, __builtin_convertvector(P##a2, bf16x4)); \
    *(u16x4*)((buf) + aw[3]) = __builtin_bit_cast(u16x4, __builtin_convertvector(P##a3, bf16x4)); \
    *(f32x4*)((buf) + bw[0]) = P##b0;                                        \
    *(f32x4*)((buf) + bw[1]) = P##b1; }

    f32x4 acc0 = {0.f,0.f,0.f,0.f}, acc1 = {0.f,0.f,0.f,0.f};
    f32x4 acc2 = {0.f,0.f,0.f,0.f}, acc3 = {0.f,0.f,0.f,0.f};

    const int arow = w * 16 + fr;
    const int aswz = (fr & 7) << 4;

#define COMPUTE(buf) {                                                       \
    _Pragma("unroll")                                                        \
    for (int ks = 0; ks < 2; ++ks) {                                         \
        u16x8 a16 = *(const u16x8*)((buf) + arow * 128 + ((ks * 64 + fg * 16) ^ aswz)); \
        bf16x8 af = __builtin_bit_cast(bf16x8, a16);                         \
        const int kb = ks * 4 + fg;                                          \
        u16x8 b0 = *(const u16x8*)((buf) + 8192 + kb * 1024 + (((0 * 16 + fr) * 16) ^ (kb << 4))); \
        acc0 = __builtin_amdgcn_mfma_f32_16x16x32_bf16(af, __builtin_bit_cast(bf16x8, b0), acc0, 0, 0, 0); \
        u16x8 b1 = *(const u16x8*)((buf) + 8192 + kb * 1024 + (((1 * 16 + fr) * 16) ^ (kb << 4))); \
        acc1 = __builtin_amdgcn_mfma_f32_16x16x32_bf16(af, __builtin_bit_cast(bf16x8, b1), acc1, 0, 0, 0); \
        u16x8 b2 = *(const u16x8*)((buf) + 8192 + kb * 1024 + (((2 * 16 + fr) * 16) ^ (kb << 4))); \
        acc2 = __builtin_amdgcn_mfma_f32_16x16x32_bf16(af, __builtin_bit_cast(bf16x8, b2), acc2, 0, 0, 0); \
        u16x8 b3 = *(const u16x8*)((buf) + 8192 + kb * 1024 + (((3 * 16 + fr) * 16) ^ (kb << 4))); \
        acc3 = __builtin_amdgcn_mfma_f32_16x16x32_bf16(af, __builtin_bit_cast(bf16x8, b3), acc3, 0, 0, 0); \
    } }

    LOADX(RA, 0);
    STOREX(RA, smem[0]);

    for (int c = 0; c < 32; c += 2) {
        LOADX(RB, c + 1);
        __syncthreads();
        COMPUTE(smem[0]);
        STOREX(RB, smem[1]);
        if (c + 2 < 32) LOADX(RA, c + 2);
        __syncthreads();
        COMPUTE(smem[1]);
        if (c + 2 < 32) STOREX(RA, smem[0]);
    }

#undef LOADX
#undef STOREX
#undef COMPUTE

    float* C = outBase + (size_t)job * (NODES * 64);
    float* Cw = C + (size_t)(n0 + w * 16 + fg * 4) * 64 + fr;
#pragma unroll
    for (int j = 0; j < 4; ++j) {
        atomicAdd(&Cw[j * 64 + 0],  acc0[j]);
        atomicAdd(&Cw[j * 64 + 16], acc1[j]);
        atomicAdd(&Cw[j * 64 + 32], acc2[j]);
        atomicAdd(&Cw[j * 64 + 48], acc3[j]);
    }
}

// ---- stage C: semantic-attention logits + schema softmax -> iccB (k-blocked)
__global__ __launch_bounds__(128) void stage_c(
    const float* __restrict__ agg, const float* __restrict__ Wa,
    const float* __restrict__ ba, const float* __restrict__ qa,
    const float* __restrict__ wsv, float* __restrict__ sacc,
    unsigned short* __restrict__ iccB)
{
    const int n = blockIdx.x;
    const int p = threadIdx.x;
    __shared__ float rs[3][2];
    __shared__ float ru[2][2];
    __shared__ float th[3][64];

    const float* h0p = agg + (size_t)n * 64;
    const float* h1p = agg + ((size_t)NODES + n) * 64;
    const float* h2p = agg + ((size_t)2 * NODES + n) * 64;
    if (p < 64) {
        th[0][p] = tanhf(h0p[p]);
        th[1][p] = tanhf(h1p[p]);
        th[2][p] = tanhf(h2p[p]);
    }
    __syncthreads();
    float a0 = ba[p], a1 = a0, a2 = a0;
#pragma unroll 8
    for (int d = 0; d < 64; ++d) {
        float w = Wa[d * 128 + p];
        a0 = fmaf(th[0][d], w, a0);
        a1 = fmaf(th[1][d], w, a1);
        a2 = fmaf(th[2][d], w, a2);
    }
    float qv = qa[p];
    float v0 = tanhf(a0) * qv, v1 = tanhf(a1) * qv, v2 = tanhf(a2) * qv;

    const float* z0 = agg + ((size_t)3 * NODES + n) * 64;
    const float* z1 = agg + ((size_t)4 * NODES + n) * 64;
    float u0 = (p < 64) ? z0[p] * wsv[p] : 0.f;
    float u1 = (p < 64) ? z1[p] * wsv[p] : 0.f;

#pragma unroll
    for (int off = 32; off; off >>= 1) {
        v0 += __shfl_down(v0, off); v1 += __shfl_down(v1, off); v2 += __shfl_down(v2, off);
        u0 += __shfl_down(u0, off); u1 += __shfl_down(u1, off);
    }
    if ((p & 63) == 0) {
        int w = p >> 6;
        rs[0][w] = v0; rs[1][w] = v1; rs[2][w] = v2;
        ru[0][w] = u0; ru[1][w] = u1;
    }
    __syncthreads();
    if (p < 3) atomicAdd(&sacc[p], rs[p][0] + rs[p][1]);

    float U0 = ru[0][0] + ru[0][1];
    float U1 = ru[1][0] + ru[1][1];
    float mx = fmaxf(U0, U1);
    float e0 = expf(U0 - mx), e1 = expf(U1 - mx);
    float inv = 1.f / (e0 + e1);
    if (p < 64) {
        float icc = (e0 * z0[p] + e1 * z1[p]) * inv;
        iccB[((size_t)(n >> 3)) * 512 + p * 8 + (n & 7)] = f2bf(icc);
    }
}

// ---- stage E: relation_agg, item-item attention, AggAttention, projection --
__global__ __launch_bounds__(256) void finalize(
    const float* __restrict__ agg, const float* __restrict__ ym,
    const float* __restrict__ sacc,
    const float* __restrict__ Wc1, const float* __restrict__ bc1, const float* __restrict__ wc2,
    const float* __restrict__ Wt1, const float* __restrict__ bt1, const float* __restrict__ wt2,
    const float* __restrict__ Wp, const float* __restrict__ bp,
    float* __restrict__ out)
{
    __shared__ float sWc[64 * 128];
    __shared__ float sWp[64 * 16];
    __shared__ float sY0[2][64], sY1[2][64];
    __shared__ float sHs0[2][64], sHs1[2][64], sHv[2][64];
    __shared__ float rA[2][2], rB[2][2];

    const int t = threadIdx.x;
    for (int i = t; i < 64 * 128; i += 256) sWc[i] = Wc1[i];
    for (int i = t; i < 64 * 16; i += 256) sWp[i] = Wp[i];

    float s0 = sacc[0] * (1.f / NODES), s1 = sacc[1] * (1.f / NODES), s2 = sacc[2] * (1.f / NODES);
    float sm = fmaxf(s0, fmaxf(s1, s2));
    float b0 = expf(s0 - sm), b1 = expf(s1 - sm), b2 = expf(s2 - sm);
    float bi = 1.f / (b0 + b1 + b2);
    b0 *= bi; b1 *= bi; b2 *= bi;

    const int sub = t >> 7;
    const int p = t & 127;
    const int wiH = p >> 6;
    const float bcv = bc1[p], wcv = wc2[p], btv = bt1[p], wtv = wt2[p];
    __syncthreads();

    for (int it = 0; it < 8; ++it) {
        const int n = blockIdx.x * 16 + it * 2 + sub;
        if (p < 64) {
            const size_t NN64 = (size_t)NODES * 64;
            sY0[sub][p] = tanhf(ym[(size_t)n * 64 + p]);
            sY1[sub][p] = tanhf(ym[NN64 + (size_t)n * 64 + p]);
            sHs0[sub][p] = b0 * tanhf(agg[(size_t)n * 64 + p])
                         + b1 * tanhf(agg[((size_t)NODES + n) * 64 + p])
                         + b2 * tanhf(agg[((size_t)2 * NODES + n) * 64 + p]);
        }
        __syncthreads();
        float ac0 = bcv, ac1 = bcv;
#pragma unroll 8
        for (int d = 0; d < 64; ++d) {
            float w = sWc[d * 128 + p];
            ac0 = fmaf(sY0[sub][d], w, ac0);
            ac1 = fmaf(sY1[sub][d], w, ac1);
        }
        float v0 = tanhf(ac0) * wcv, v1 = tanhf(ac1) * wcv;
#pragma unroll
        for (int off = 32; off; off >>= 1) { v0 += __shfl_down(v0, off); v1 += __shfl_down(v1, off); }
        if ((p & 63) == 0) { rA[sub][wiH] = v0; rB[sub][wiH] = v1; }
        __syncthreads();
        float wm0 = rA[sub][0] + rA[sub][1];
        float wm1 = rB[sub][0] + rB[sub][1];
        float mm = fmaxf(wm0, wm1);
        float g0 = expf(wm0 - mm), g1 = expf(wm1 - mm);
        float gi = 1.f / (g0 + g1);
        g0 *= gi; g1 *= gi;
        if (p < 64) sHs1[sub][p] = g0 * sY0[sub][p] + g1 * sY1[sub][p];
        __syncthreads();

        float at0 = btv, at1 = btv;
#pragma unroll 8
        for (int d = 0; d < 64; ++d) {
            float w = Wt1[d * 128 + p];
            at0 = fmaf(sHs0[sub][d], w, at0);
            at1 = fmaf(sHs1[sub][d], w, at1);
        }
        float q0 = tanhf(at0) * wtv, q1 = tanhf(at1) * wtv;
#pragma unroll
        for (int off = 32; off; off >>= 1) { q0 += __shfl_down(q0, off); q1 += __shfl_down(q1, off); }
        if ((p & 63) == 0) { rA[sub][wiH] = q0; rB[sub][wiH] = q1; }
        __syncthreads();
        float t0 = rA[sub][0] + rA[sub][1];
        float t1 = rB[sub][0] + rB[sub][1];
        float tm = fmaxf(t0, t1);
        float c0 = expf(t0 - tm), c1 = expf(t1 - tm);
        float ci = 1.f / (c0 + c1);
        c0 *= ci; c1 *= ci;
        if (p < 64) {
            float H = c0 * sHs0[sub][p] + c1 * sHs1[sub][p];
            sHv[sub][p] = H;
            out[(size_t)NODES * 16 + (size_t)n * 64 + p] = H;
        }
        __syncthreads();
        if (p < 16) {
            float a = bp[p];
#pragma unroll 8
            for (int d = 0; d < 64; ++d) a = fmaf(sHv[sub][d], sWp[d * 16 + p], a);
            out[(size_t)n * 16 + p] = a;
        }
        __syncthreads();
    }
}

extern "C" void kernel_launch(void* const* d_in, const int* in_sizes, int n_in,
                              void* d_out, int out_size, void* d_ws, size_t ws_size,
                              hipStream_t stream)
{
    const float* f0   = (const float*)d_in[0];
    const float* f1   = (const float*)d_in[1];
    const float* adjS = (const float*)d_in[2];
    const float* adjM = (const float*)d_in[3];
    const float* adjK = (const float*)d_in[4];
    const float* Wm0  = (const float*)d_in[5];
    const float* bm0  = (const float*)d_in[6];
    const float* Wm1  = (const float*)d_in[7];
    const float* bm1  = (const float*)d_in[8];
    const float* Wa   = (const float*)d_in[9];
    const float* ba   = (const float*)d_in[10];
    const float* qa   = (const float*)d_in[11];
    const float* wsv  = (const float*)d_in[12];
    const float* Wc1  = (const float*)d_in[13];
    const float* bc1  = (const float*)d_in[14];
    const float* wc2  = (const float*)d_in[15];
    const float* Wt1  = (const float*)d_in[16];
    const float* bt1  = (const float*)d_in[17];
    const float* wt2  = (const float*)d_in[18];
    const float* Wp   = (const float*)d_in[19];
    const float* bpv  = (const float*)d_in[20];
    float* out = (float*)d_out;

    // workspace layout:
    //   0        hB0   512 KB (k-blocked bf16)
    //   524288   hB1   512 KB
    //   1048576  iccB  512 KB
    //   1572864  agg   5 MB  (raw sums; atomic-accumulated)
    //   6815744  ym    2 MB  (raw sums; atomic-accumulated)
    //   8912896  sacc  64 B
    //   8913920  adjB16 7 x 32 MB = 224 MB  (only if ws_size permits)
    char* ws = (char*)d_ws;
    unsigned short* hB0  = (unsigned short*)(ws);
    unsigned short* hB1  = (unsigned short*)(ws + 524288);
    unsigned short* iccB = (unsigned short*)(ws + 1048576);
    float* agg           = (float*)(ws + 1572864);
    float* ym            = (float*)(ws + 6815744);
    float* sacc          = (float*)(ws + 8912896);
    unsigned short* adjB = (unsigned short*)(ws + 8913920);
    const bool useCvt = ws_size >= (8913920ULL + 7ULL * NN * 2ULL);

    hipMemsetAsync(agg, 0, 7 * 1048576, stream);   // agg + ym contiguous
    hipMemsetAsync(sacc, 0, 64, stream);
    prep_h<<<dim3(1024), dim3(256), 0, stream>>>(f0, f1, Wm0, bm0, Wm1, bm1, hB0, hB1);

    if (useCvt) {
        cvt_adj<<<dim3(1024, 7), dim3(256), 0, stream>>>(adjS, adjM, adjK, adjB);
        // gemm5: slots 0..4 (M0,M1,M2,K0,K1); 64 rg x 2 kh
        adj_gemm_b16<<<dim3(128, 5), dim3(256), 0, stream>>>(
            adjB, 0, hB0, hB1, 3, agg, 1);
        stage_c<<<dim3(4096), dim3(128), 0, stream>>>(agg, Wa, ba, qa, wsv, sacc, iccB);
        // gemm2: slots 5..6 (S0,S1); 64 rg x 4 kh
        adj_gemm_b16<<<dim3(256, 2), dim3(256), 0, stream>>>(
            adjB, 5, iccB, iccB, 5, ym, 2);
    } else {
        const size_t NNs = (size_t)NODES * NODES;
        adj_gemm_f32<<<dim3(128, 5), dim3(256), 0, stream>>>(
            adjM, adjM + NNs, adjM + 2 * NNs, adjK, adjK + NNs,
            hB0, hB1, 3, agg);
        stage_c<<<dim3(4096), dim3(128), 0, stream>>>(agg, Wa, ba, qa, wsv, sacc, iccB);
        adj_gemm_f32<<<dim3(128, 2), dim3(256), 0, stream>>>(
            adjS, adjS + NNs, adjS, adjS, adjS,
            iccB, iccB, 5, ym);
    }
    finalize<<<dim3(256), dim3(256), 0, stream>>>(
        agg, ym, sacc, Wc1, bc1, wc2, Wt1, bt1, wt2, Wp, bpv, out);
}

// Round 11
// 251.876 us; speedup vs baseline: 1.4141x; 1.4141x over previous
//
#include <hip/hip_runtime.h>

#define NODES 4096

typedef float f32x4 __attribute__((ext_vector_type(4)));
typedef __bf16 bf16x4 __attribute__((ext_vector_type(4)));
typedef __bf16 bf16x8 __attribute__((ext_vector_type(8)));
typedef unsigned short u16x8 __attribute__((ext_vector_type(8)));
typedef unsigned short u16x4 __attribute__((ext_vector_type(4)));

__device__ __forceinline__ unsigned short f2bf(float x) {
    unsigned u = __builtin_bit_cast(unsigned, x);
    return (unsigned short)((u + 0x7fffu + ((u >> 16) & 1u)) >> 16);
}

// ---- stage A: h = tanh(x@Wm + bm), stored k-blocked bf16: hB[n/8][64 d][8 n]
__global__ __launch_bounds__(256) void prep_h(
    const float* __restrict__ f0, const float* __restrict__ f1,
    const float* __restrict__ Wm0, const float* __restrict__ bm0,
    const float* __restrict__ Wm1, const float* __restrict__ bm1,
    unsigned short* __restrict__ hB0, unsigned short* __restrict__ hB1)
{
    const int d = threadIdx.x & 63;
    int n = blockIdx.x * 4 + (threadIdx.x >> 6);
    n = __builtin_amdgcn_readfirstlane(n);
    const float* r0 = f0 + (size_t)n * 256;
    float a0 = bm0[d];
#pragma unroll 8
    for (int k = 0; k < 256; ++k) a0 = fmaf(r0[k], Wm0[k * 64 + d], a0);
    hB0[((size_t)(n >> 3)) * 512 + d * 8 + (n & 7)] = f2bf(tanhf(a0));
    const float* r1 = f1 + (size_t)n * 128;
    float a1 = bm1[d];
#pragma unroll 8
    for (int k = 0; k < 128; ++k) a1 = fmaf(r1[k], Wm1[k * 64 + d], a1);
    hB1[((size_t)(n >> 3)) * 512 + d * 8 + (n & 7)] = f2bf(tanhf(a1));
}

// ---- adjacency GEMM (f32 A): round-8 validated kernel, K-split templated ----
// Block = 64 rows x 64 cols, 4 waves; wave w computes rows w*16..+15. Chunk =
// 64 k: A [64r][64k] f32->bf16 8KB + B (k-blocked hB) 8KB, double-buffered
// (32KB LDS). Loads pinned BEFORE the per-chunk __syncthreads (in flight
// across compute). Raw sums atomicAdd'ed (K-split adders); tanh deferred.
// Swizzles (both-sides, reg-staged): A byte ^= (r&7)<<4 within 128B row;
// B byte ^= kb<<4 within 1KB k-block. r8 measured: 2.69 TB/s read = 97% of
// this box's measured streaming-read wall (cvt_adj probe, r10: 2.75 TB/s).
// KHBITS: 1 -> 640 blocks (2.5/CU) for the 5-job phase;
//         2 -> 512 blocks (2/CU)  for the 2-job phase (r8 ran 1/CU: latency-bound).
template<int KHBITS>
__global__ __launch_bounds__(256) void adj_gemm_f32(
    const float* __restrict__ A0, const float* __restrict__ A1,
    const float* __restrict__ A2, const float* __restrict__ A3,
    const float* __restrict__ A4,
    const unsigned short* __restrict__ hBa, const unsigned short* __restrict__ hBb,
    int split, float* __restrict__ outBase)
{
    __shared__ __align__(16) char smem[2][16384];   // [buf][A 8KB | B 8KB]

    const int job = blockIdx.y;
    const float* adj = job == 0 ? A0 : job == 1 ? A1 : job == 2 ? A2 : job == 3 ? A3 : A4;
    const unsigned short* hB = (job < split) ? hBa : hBb;

    const int group = blockIdx.x >> KHBITS;
    const int kh = blockIdx.x & ((1 << KHBITS) - 1);
    const int n0 = group * 64;
    constexpr int KLEN = NODES >> KHBITS;
    constexpr int NC = KLEN >> 6;        // chunks of 64 k
    const int kbeg = kh * KLEN;

    const int t = threadIdx.x;
    const int lane = t & 63, w = t >> 6;
    const int fr = lane & 15, fg = lane >> 4;

    // A staging: granule g -> row g*16+(t>>4), 16B f32 at colbyte (t&15)*16
    const char* aSrcT = (const char*)adj
        + ((size_t)(n0 + (t >> 4)) * NODES + kbeg) * 4 + (size_t)(t & 15) * 16;
    // B staging: k-blocked contiguous (hB[n/8][64d][8n])
    const char* bSrcT = (const char*)hB + ((size_t)(kbeg >> 3)) * 1024 + (size_t)t * 16;

    int aw[4];
#pragma unroll
    for (int g = 0; g < 4; ++g) {
        const int r = g * 16 + (t >> 4);
        aw[g] = r * 128 + ((((t & 15) * 8)) ^ ((r & 7) << 4));
    }
    int bw[2];
#pragma unroll
    for (int j = 0; j < 2; ++j) {
        const int L = (t + 256 * j) * 16;
        const int kb = L >> 10;
        const int d = (L >> 4) & 63;
        bw[j] = 8192 + kb * 1024 + ((d * 16) ^ (kb << 4));
    }

    f32x4 RAa0, RAa1, RAa2, RAa3, RAb0, RAb1;
    f32x4 RBa0, RBa1, RBa2, RBa3, RBb0, RBb1;

#define LOADX(P, c) {                                                        \
    P##a0 = *(const f32x4*)(aSrcT + 0 * 262144 + (size_t)(c) * 256);         \
    P##a1 = *(const f32x4*)(aSrcT + 1 * 262144 + (size_t)(c) * 256);         \
    P##a2 = *(const f32x4*)(aSrcT + 2 * 262144 + (size_t)(c) * 256);         \
    P##a3 = *(const f32x4*)(aSrcT + 3 * 262144 + (size_t)(c) * 256);         \
    P##b0 = *(const f32x4*)(bSrcT + (size_t)(c) * 8192);                     \
    P##b1 = *(const f32x4*)(bSrcT + 4096 + (size_t)(c) * 8192); }

#define STOREX(P, buf) {                                                     \
    *(u16x4*)((buf) + aw[0]) = __builtin_bit_cast(u16x4, __builtin_convertvector(P##a0, bf16x4)); \
    *(u16x4*)((buf) + aw[1]) = __builtin_bit_cast(u16x4, __builtin_convertvector(P##a1, bf16x4)); \
    *(u16x4*)((buf) + aw[2]) = __builtin_bit_cast(u16x4, __builtin_convertvector(P##a2, bf16x4)); \
    *(u16x4*)((buf) + aw[3]) = __builtin_bit_cast(u16x4, __builtin_convertvector(P##a3, bf16x4)); \
    *(f32x4*)((buf) + bw[0]) = P##b0;                                        \
    *(f32x4*)((buf) + bw[1]) = P##b1; }

    f32x4 acc0 = {0.f,0.f,0.f,0.f}, acc1 = {0.f,0.f,0.f,0.f};
    f32x4 acc2 = {0.f,0.f,0.f,0.f}, acc3 = {0.f,0.f,0.f,0.f};

    const int arow = w * 16 + fr;
    const int aswz = (fr & 7) << 4;

#define COMPUTE(buf) {                                                       \
    _Pragma("unroll")                                                        \
    for (int ks = 0; ks < 2; ++ks) {                                         \
        u16x8 a16 = *(const u16x8*)((buf) + arow * 128 + ((ks * 64 + fg * 16) ^ aswz)); \
        bf16x8 af = __builtin_bit_cast(bf16x8, a16);                         \
        const int kb = ks * 4 + fg;                                          \
        u16x8 b0 = *(const u16x8*)((buf) + 8192 + kb * 1024 + (((0 * 16 + fr) * 16) ^ (kb << 4))); \
        acc0 = __builtin_amdgcn_mfma_f32_16x16x32_bf16(af, __builtin_bit_cast(bf16x8, b0), acc0, 0, 0, 0); \
        u16x8 b1 = *(const u16x8*)((buf) + 8192 + kb * 1024 + (((1 * 16 + fr) * 16) ^ (kb << 4))); \
        acc1 = __builtin_amdgcn_mfma_f32_16x16x32_bf16(af, __builtin_bit_cast(bf16x8, b1), acc1, 0, 0, 0); \
        u16x8 b2 = *(const u16x8*)((buf) + 8192 + kb * 1024 + (((2 * 16 + fr) * 16) ^ (kb << 4))); \
        acc2 = __builtin_amdgcn_mfma_f32_16x16x32_bf16(af, __builtin_bit_cast(bf16x8, b2), acc2, 0, 0, 0); \
        u16x8 b3 = *(const u16x8*)((buf) + 8192 + kb * 1024 + (((3 * 16 + fr) * 16) ^ (kb << 4))); \
        acc3 = __builtin_amdgcn_mfma_f32_16x16x32_bf16(af, __builtin_bit_cast(bf16x8, b3), acc3, 0, 0, 0); \
    } }

    // prologue: chunk 0 -> buf0
    LOADX(RA, 0);
    STOREX(RA, smem[0]);

    for (int c = 0; c < NC; c += 2) {
        LOADX(RB, c + 1);                // pinned before barrier: in flight over compute
        __syncthreads();
        COMPUTE(smem[0]);
        STOREX(RB, smem[1]);
        if (c + 2 < NC) LOADX(RA, c + 2);
        __syncthreads();
        COMPUTE(smem[1]);
        if (c + 2 < NC) STOREX(RA, smem[0]);
    }

#undef LOADX
#undef STOREX
#undef COMPUTE

    // acc[s][j] -> C[n0 + w*16 + fg*4 + j][s*16 + fr], atomic K-split combine
    float* C = outBase + (size_t)job * (NODES * 64);
    float* Cw = C + (size_t)(n0 + w * 16 + fg * 4) * 64 + fr;
#pragma unroll
    for (int j = 0; j < 4; ++j) {
        atomicAdd(&Cw[j * 64 + 0],  acc0[j]);
        atomicAdd(&Cw[j * 64 + 16], acc1[j]);
        atomicAdd(&Cw[j * 64 + 32], acc2[j]);
        atomicAdd(&Cw[j * 64 + 48], acc3[j]);
    }
}

// ---- stage C: semantic-attention logits + schema softmax -> iccB (k-blocked)
// agg holds RAW sums; hr = tanh(raw) applied here. zk is raw per reference.
__global__ __launch_bounds__(128) void stage_c(
    const float* __restrict__ agg, const float* __restrict__ Wa,
    const float* __restrict__ ba, const float* __restrict__ qa,
    const float* __restrict__ wsv, float* __restrict__ sacc,
    unsigned short* __restrict__ iccB)
{
    const int n = blockIdx.x;
    const int p = threadIdx.x;
    __shared__ float rs[3][2];
    __shared__ float ru[2][2];
    __shared__ float th[3][64];

    const float* h0p = agg + (size_t)n * 64;
    const float* h1p = agg + ((size_t)NODES + n) * 64;
    const float* h2p = agg + ((size_t)2 * NODES + n) * 64;
    if (p < 64) {
        th[0][p] = tanhf(h0p[p]);
        th[1][p] = tanhf(h1p[p]);
        th[2][p] = tanhf(h2p[p]);
    }
    __syncthreads();
    float a0 = ba[p], a1 = a0, a2 = a0;
#pragma unroll 8
    for (int d = 0; d < 64; ++d) {
        float w = Wa[d * 128 + p];
        a0 = fmaf(th[0][d], w, a0);
        a1 = fmaf(th[1][d], w, a1);
        a2 = fmaf(th[2][d], w, a2);
    }
    float qv = qa[p];
    float v0 = tanhf(a0) * qv, v1 = tanhf(a1) * qv, v2 = tanhf(a2) * qv;

    const float* z0 = agg + ((size_t)3 * NODES + n) * 64;
    const float* z1 = agg + ((size_t)4 * NODES + n) * 64;
    float u0 = (p < 64) ? z0[p] * wsv[p] : 0.f;
    float u1 = (p < 64) ? z1[p] * wsv[p] : 0.f;

#pragma unroll
    for (int off = 32; off; off >>= 1) {
        v0 += __shfl_down(v0, off); v1 += __shfl_down(v1, off); v2 += __shfl_down(v2, off);
        u0 += __shfl_down(u0, off); u1 += __shfl_down(u1, off);
    }
    if ((p & 63) == 0) {
        int w = p >> 6;
        rs[0][w] = v0; rs[1][w] = v1; rs[2][w] = v2;
        ru[0][w] = u0; ru[1][w] = u1;
    }
    __syncthreads();
    if (p < 3) atomicAdd(&sacc[p], rs[p][0] + rs[p][1]);

    float U0 = ru[0][0] + ru[0][1];
    float U1 = ru[1][0] + ru[1][1];
    float mx = fmaxf(U0, U1);
    float e0 = expf(U0 - mx), e1 = expf(U1 - mx);
    float inv = 1.f / (e0 + e1);
    if (p < 64) {
        float icc = (e0 * z0[p] + e1 * z1[p]) * inv;
        iccB[((size_t)(n >> 3)) * 512 + p * 8 + (n & 7)] = f2bf(icc);
    }
}

// ---- stage E: relation_agg, item-item attention, AggAttention, projection --
// ym holds raw sums (atomic-accumulated); tanh applied here. agg raw -> tanh.
__global__ __launch_bounds__(256) void finalize(
    const float* __restrict__ agg, const float* __restrict__ ym,
    const float* __restrict__ sacc,
    const float* __restrict__ Wc1, const float* __restrict__ bc1, const float* __restrict__ wc2,
    const float* __restrict__ Wt1, const float* __restrict__ bt1, const float* __restrict__ wt2,
    const float* __restrict__ Wp, const float* __restrict__ bp,
    float* __restrict__ out)
{
    __shared__ float sWc[64 * 128];
    __shared__ float sWp[64 * 16];
    __shared__ float sY0[2][64], sY1[2][64];
    __shared__ float sHs0[2][64], sHs1[2][64], sHv[2][64];
    __shared__ float rA[2][2], rB[2][2];

    const int t = threadIdx.x;
    for (int i = t; i < 64 * 128; i += 256) sWc[i] = Wc1[i];
    for (int i = t; i < 64 * 16; i += 256) sWp[i] = Wp[i];

    float s0 = sacc[0] * (1.f / NODES), s1 = sacc[1] * (1.f / NODES), s2 = sacc[2] * (1.f / NODES);
    float sm = fmaxf(s0, fmaxf(s1, s2));
    float b0 = expf(s0 - sm), b1 = expf(s1 - sm), b2 = expf(s2 - sm);
    float bi = 1.f / (b0 + b1 + b2);
    b0 *= bi; b1 *= bi; b2 *= bi;

    const int sub = t >> 7;
    const int p = t & 127;
    const int wiH = p >> 6;
    const float bcv = bc1[p], wcv = wc2[p], btv = bt1[p], wtv = wt2[p];
    __syncthreads();

    for (int it = 0; it < 8; ++it) {
        const int n = blockIdx.x * 16 + it * 2 + sub;
        if (p < 64) {
            const size_t NN64 = (size_t)NODES * 64;
            sY0[sub][p] = tanhf(ym[(size_t)n * 64 + p]);
            sY1[sub][p] = tanhf(ym[NN64 + (size_t)n * 64 + p]);
            sHs0[sub][p] = b0 * tanhf(agg[(size_t)n * 64 + p])
                         + b1 * tanhf(agg[((size_t)NODES + n) * 64 + p])
                         + b2 * tanhf(agg[((size_t)2 * NODES + n) * 64 + p]);
        }
        __syncthreads();
        float ac0 = bcv, ac1 = bcv;
#pragma unroll 8
        for (int d = 0; d < 64; ++d) {
            float w = sWc[d * 128 + p];
            ac0 = fmaf(sY0[sub][d], w, ac0);
            ac1 = fmaf(sY1[sub][d], w, ac1);
        }
        float v0 = tanhf(ac0) * wcv, v1 = tanhf(ac1) * wcv;
#pragma unroll
        for (int off = 32; off; off >>= 1) { v0 += __shfl_down(v0, off); v1 += __shfl_down(v1, off); }
        if ((p & 63) == 0) { rA[sub][wiH] = v0; rB[sub][wiH] = v1; }
        __syncthreads();
        float wm0 = rA[sub][0] + rA[sub][1];
        float wm1 = rB[sub][0] + rB[sub][1];
        float mm = fmaxf(wm0, wm1);
        float g0 = expf(wm0 - mm), g1 = expf(wm1 - mm);
        float gi = 1.f / (g0 + g1);
        g0 *= gi; g1 *= gi;
        if (p < 64) sHs1[sub][p] = g0 * sY0[sub][p] + g1 * sY1[sub][p];
        __syncthreads();

        float at0 = btv, at1 = btv;
#pragma unroll 8
        for (int d = 0; d < 64; ++d) {
            float w = Wt1[d * 128 + p];
            at0 = fmaf(sHs0[sub][d], w, at0);
            at1 = fmaf(sHs1[sub][d], w, at1);
        }
        float q0 = tanhf(at0) * wtv, q1 = tanhf(at1) * wtv;
#pragma unroll
        for (int off = 32; off; off >>= 1) { q0 += __shfl_down(q0, off); q1 += __shfl_down(q1, off); }
        if ((p & 63) == 0) { rA[sub][wiH] = q0; rB[sub][wiH] = q1; }
        __syncthreads();
        float t0 = rA[sub][0] + rA[sub][1];
        float t1 = rB[sub][0] + rB[sub][1];
        float tm = fmaxf(t0, t1);
        float c0 = expf(t0 - tm), c1 = expf(t1 - tm);
        float ci = 1.f / (c0 + c1);
        c0 *= ci; c1 *= ci;
        if (p < 64) {
            float H = c0 * sHs0[sub][p] + c1 * sHs1[sub][p];
            sHv[sub][p] = H;
            out[(size_t)NODES * 16 + (size_t)n * 64 + p] = H;
        }
        __syncthreads();
        if (p < 16) {
            float a = bp[p];
#pragma unroll 8
            for (int d = 0; d < 64; ++d) a = fmaf(sHv[sub][d], sWp[d * 16 + p], a);
            out[(size_t)n * 16 + p] = a;
        }
        __syncthreads();
    }
}

extern "C" void kernel_launch(void* const* d_in, const int* in_sizes, int n_in,
                              void* d_out, int out_size, void* d_ws, size_t ws_size,
                              hipStream_t stream)
{
    const float* f0   = (const float*)d_in[0];
    const float* f1   = (const float*)d_in[1];
    const float* adjS = (const float*)d_in[2];
    const float* adjM = (const float*)d_in[3];
    const float* adjK = (const float*)d_in[4];
    const float* Wm0  = (const float*)d_in[5];
    const float* bm0  = (const float*)d_in[6];
    const float* Wm1  = (const float*)d_in[7];
    const float* bm1  = (const float*)d_in[8];
    const float* Wa   = (const float*)d_in[9];
    const float* ba   = (const float*)d_in[10];
    const float* qa   = (const float*)d_in[11];
    const float* wsv  = (const float*)d_in[12];
    const float* Wc1  = (const float*)d_in[13];
    const float* bc1  = (const float*)d_in[14];
    const float* wc2  = (const float*)d_in[15];
    const float* Wt1  = (const float*)d_in[16];
    const float* bt1  = (const float*)d_in[17];
    const float* wt2  = (const float*)d_in[18];
    const float* Wp   = (const float*)d_in[19];
    const float* bpv  = (const float*)d_in[20];
    float* out = (float*)d_out;

    // workspace layout (bytes) — total ~8.5 MB:
    //   0        hB0   512 KB (k-blocked bf16)
    //   524288   hB1   512 KB
    //   1048576  iccB  512 KB
    //   1572864  agg   5 MB  (raw sums hr0..2, zk0..1; atomic-accumulated)
    //   6815744  ym    2 MB  (raw sums, 2 slots; atomic-accumulated)
    //   8912896  sacc  64 B  (contiguous with ym -> single memset)
    char* ws = (char*)d_ws;
    unsigned short* hB0  = (unsigned short*)(ws);
    unsigned short* hB1  = (unsigned short*)(ws + 524288);
    unsigned short* iccB = (unsigned short*)(ws + 1048576);
    float* agg           = (float*)(ws + 1572864);
    float* ym            = (float*)(ws + 6815744);
    float* sacc          = (float*)(ws + 8912896);

    hipMemsetAsync(agg, 0, 7 * 1048576 + 64, stream);  // agg + ym + sacc contiguous
    prep_h<<<dim3(1024), dim3(256), 0, stream>>>(f0, f1, Wm0, bm0, Wm1, bm1, hB0, hB1);

    const size_t NNs = (size_t)NODES * NODES;
    // gemm5: hr[0..2] raw = adj_meta[r]@h0, zk[0..1] = adj_schema[k]@h1.
    // 64 rowgroups x 2 khalves x 5 jobs = 640 blocks (2.5/CU) — at the wall (r8).
    adj_gemm_f32<1><<<dim3(128, 5), dim3(256), 0, stream>>>(
        adjM, adjM + NNs, adjM + 2 * NNs, adjK, adjK + NNs,
        hB0, hB1, 3, agg);
    stage_c<<<dim3(4096), dim3(128), 0, stream>>>(agg, Wa, ba, qa, wsv, sacc, iccB);
    // gemm2: ym raw = adj_same[m]@icc. 64 rg x 4 kh x 2 jobs = 512 blocks (2/CU);
    // r8 ran this at 1 block/CU -> latency-bound (~2x off the wall).
    adj_gemm_f32<2><<<dim3(256, 2), dim3(256), 0, stream>>>(
        adjS, adjS + NNs, adjS, adjS, adjS,
        iccB, iccB, 5, ym);
    finalize<<<dim3(256), dim3(256), 0, stream>>>(
        agg, ym, sacc, Wc1, bc1, wc2, Wt1, bt1, wt2, Wp, bpv, out);
}